// Round 13
// baseline (189.612 us; speedup 1.0000x reference)
//
#include <hip/hip_runtime.h>
#include <hip/hip_bf16.h>
#include <math.h>

#define BB 8
#define NN 512
#define DD 256
#define BNT 4096   // B*N

typedef __attribute__((ext_vector_type(8))) short short8;
typedef __attribute__((ext_vector_type(4))) float f32x4;

// Workspace layout (float offsets). ~18 MB.
#define OFF_S0B   0u          // bf16 [4096][256]      s0 row-major (gemmT B)
#define OFF_TT    524288u     // bf16 [8][256][3072]   TT[b][e][r*512+i] = T_r[i][e]+relb_r[e]
#define OFF_WCT   6815744u    // bf16 [256][1536]      WcT[e][r*256+d] = relW[r][d][e]
#define OFF_WBT   7012352u    // bf16 [1024][256]      Wbig^T (c rows, k=d)
#define OFF_BB    7143424u    // fp32 [1024]           h1b|outb
#define OFF_REL   7144448u    // u8   [8][512][512]    relation codes (self=6)

// d_out layout (floats)
#define OUT0_OFF   0u        // output  [8][512][256]
#define INTERP_OFF 1048576u  // interp  [3][4096]
#define SYM_OFF    1060864u  // symbols [8][512][256]

__device__ __forceinline__ float gelu_exact(float x) {
    return 0.5f * x * (1.0f + erff(x * 0.70710678118654752f));
}

__device__ __forceinline__ ushort f2bf(float x) {
    __hip_bfloat16 h = __float2bfloat16(x);
    union { __hip_bfloat16 b; ushort u; } cv;
    cv.b = h;
    return cv.u;
}

// Branch-free classification (reference if/elif priority, applied in reverse).
__device__ __forceinline__ int rel_of(float dx, float dy) {
    int r = (fabsf(dx) < 0.3f && fabsf(dy) < 0.3f) ? 4 : 5;
    r = (dx >  0.5f) ? 3 : r;
    r = (dx < -0.5f) ? 2 : r;
    r = (dy < -0.5f) ? 1 : r;
    r = (dy >  0.5f) ? 0 : r;
    return r;
}

// ======================= LDS-free 64x64 MFMA tile =========================
// 4 waves 2x2; wave computes 2x2 of 16x16x32. Both operands have contiguous
// K in memory, so each lane loads its MFMA fragment DIRECTLY from global
// (L2-resident): A[m=l15][k=quad*8+j] = 16B, B[n=l15][k=quad*8+j] = 16B.
// No LDS, no __syncthreads: the K-loop is a free-running load+MFMA stream
// the compiler pipelines with vmcnt; waves never co-stall on barriers.
// C/D: col(n)=l15, row(m)=quad*4+reg (m89/m91-verified mappings).
#define TILE_IDS()                                             \
    const int lane = tid & 63, w = tid >> 6;                   \
    const int wm = w >> 1, wn = w & 1;                         \
    const int quad = lane >> 4, l15 = lane & 15;

#define ACC_INIT()                                             \
    f32x4 acc[2][2];                                           \
    _Pragma("unroll") for (int mt = 0; mt < 2; mt++)           \
    _Pragma("unroll") for (int nt = 0; nt < 2; nt++)           \
        acc[mt][nt] = (f32x4){0.f, 0.f, 0.f, 0.f};

// ---------------------------------------------------------------- front ---
// Fused prep (blocks 0..1535) + gather (1536..5631) + classify (5632..6143).
// Weight builds read COALESCED and write scattered (stores don't stall).
__global__ __launch_bounds__(256) void front_kernel(
    const int* __restrict__ ids, const float* __restrict__ positions,
    const float* __restrict__ symt, const float* __restrict__ layt,
    const float* __restrict__ relW, const float* __restrict__ h1W,
    const float* __restrict__ outW, const float* __restrict__ h1b,
    const float* __restrict__ outb, const float* __restrict__ h2b,
    ushort* __restrict__ WcT, ushort* __restrict__ WbT,
    float* __restrict__ bbig, float* __restrict__ outI,
    float* __restrict__ symOut, ushort* __restrict__ s0b,
    unsigned char* __restrict__ rel)
{
    __shared__ float px[NN], py[NN];
    int blk = blockIdx.x, tid = threadIdx.x;
    if (blk < 1536) {
        int idx = blk * 256 + tid;               // 393216
        {
            // WcT[e][rd] = relW[rd][e]  (read coalesced over idx)
            int rd = idx >> 8, e = idx & 255;
            WcT[(size_t)e * 1536 + rd] = f2bf(relW[idx]);
        }
        if (idx < 196608) {
            // h1W flat [r][d][e] -> WbT[(r*256+e)][d]
            int r = idx >> 16, rem = idx & 65535;
            int d = rem >> 8, e = rem & 255;
            WbT[(size_t)(r * 256 + e) * DD + d] = f2bf(h1W[idx]);
        } else if (idx < 262144) {
            // outW flat [d][c'] -> WbT[768+c'][d]
            int idx2 = idx - 196608;
            int d = idx2 >> 8, c = idx2 & 255;
            WbT[(size_t)(768 + c) * DD + d] = f2bf(outW[idx2]);
        }
        if (idx < 3 * BNT) outI[idx] = h2b[idx >> 12];
        if (idx < 1024) bbig[idx] = (idx < 768) ? h1b[idx] : outb[idx - 768];
    } else if (blk < 5632) {
        int row = blk - 1536;                    // [0,4096)
        int id = ids[row];
        float v = symt[(size_t)id * DD + tid] + layt[(size_t)id * DD + tid];
        symOut[(size_t)row * DD + tid] = v;
        s0b[(size_t)row * DD + tid] = f2bf(v);
    } else {
        int blk2 = blk - 5632;                   // [0,512)
        int b = blk2 >> 6;
        int j0 = (blk2 & 63) << 3;
        int jl = tid >> 5, sub = tid & 31;       // 8 j's x 32 workers x 16 i's
        for (int i = tid; i < NN; i += 256) {
            float2 p = ((const float2*)positions)[b * NN + i];
            px[i] = p.x; py[i] = p.y;
        }
        __syncthreads();
        int j = j0 + jl;
        float xj = px[j], yj = py[j];
        union { unsigned char u8[16]; uint4 v; } codes;
#pragma unroll
        for (int t = 0; t < 16; t++) {
            int i = sub * 16 + t;
            int r = rel_of(xj - px[i], yj - py[i]);
            r = (i == j) ? 6 : r;
            codes.u8[t] = (unsigned char)r;
        }
        *(uint4*)&rel[((size_t)(b * NN + j)) * NN + sub * 16] = codes.v;
    }
}

// ----------------------------------------------------------------- gemmT --
// TT[b][e][r*512+i] = sum_d relW[r][d][e]*s0[b][i][d] + relb[r][e]
// LDS-free direct fragment loads. Grid (8 it, 24 rm, 8 b) = 1536 blocks.
__global__ __launch_bounds__(256) void gemmT_kernel(
    const ushort* __restrict__ WcT, const ushort* __restrict__ s0b,
    const float* __restrict__ relb, ushort* __restrict__ TT)
{
    int tid = threadIdx.x;
    int b = blockIdx.z;
    int rowM0 = blockIdx.y * 64;           // in [0,1536): r*256+e
    int col0 = blockIdx.x * 64;            // i tile
    int r = rowM0 >> 8, e0 = rowM0 & 255;
    TILE_IDS();
    ACC_INIT();
    const ushort* pA[2];
    const ushort* pB[2];
#pragma unroll
    for (int mt = 0; mt < 2; mt++)
        pA[mt] = WcT + (size_t)(e0 + wm * 32 + mt * 16 + l15) * 1536
                     + r * 256 + quad * 8;
#pragma unroll
    for (int nt = 0; nt < 2; nt++)
        pB[nt] = s0b + ((size_t)(b * NN) + col0 + wn * 32 + nt * 16 + l15) * DD
                     + quad * 8;
#pragma unroll
    for (int i = 0; i < 8; i++) {
        short8 af[2], bf[2];
#pragma unroll
        for (int mt = 0; mt < 2; mt++) af[mt] = *(const short8*)(pA[mt] + i * 32);
#pragma unroll
        for (int nt = 0; nt < 2; nt++) bf[nt] = *(const short8*)(pB[nt] + i * 32);
#pragma unroll
        for (int mt = 0; mt < 2; mt++)
#pragma unroll
            for (int nt = 0; nt < 2; nt++)
                acc[mt][nt] = __builtin_amdgcn_mfma_f32_16x16x32_bf16(
                    af[mt], bf[nt], acc[mt][nt], 0, 0, 0);
    }
#pragma unroll
    for (int mt = 0; mt < 2; mt++)
#pragma unroll
        for (int nt = 0; nt < 2; nt++)
#pragma unroll
            for (int v = 0; v < 4; v++) {
                int e = e0 + wm * 32 + mt * 16 + quad * 4 + v;
                int i = col0 + wn * 32 + nt * 16 + l15;
                TT[((size_t)(b * DD) + e) * 3072 + r * 512 + i] =
                    f2bf(acc[mt][nt][v] + relb[r * DD + e]);
            }
}

// ------------------------------------------------------------- agg gemm ---
// symOut[b*512+j][e] += sum_{r,i} 1[rel(i,j)=r] * TT[b][e][r*512+i]
// One-hot A built in-register from 8B code loads; B fragments loaded
// directly from TT. 3 K-slices (rg, K=1024), grid (4 et, 8 jt, 24 b*rg).
__global__ __launch_bounds__(256) void agg_gemm(
    const unsigned char* __restrict__ rel, const ushort* __restrict__ TT,
    float* __restrict__ symOut)
{
    int tid = threadIdx.x;
    int z = blockIdx.z;
    int b = z / 3, rg = z - b * 3;
    int row0 = blockIdx.y * 64, col0 = blockIdx.x * 64;
    TILE_IDS();
    ACC_INIT();
    const unsigned char* pC[2];
#pragma unroll
    for (int mt = 0; mt < 2; mt++)
        pC[mt] = rel + ((size_t)(b * NN + row0 + wm * 32 + mt * 16 + l15)) * NN;
    const ushort* pB[2];
#pragma unroll
    for (int nt = 0; nt < 2; nt++)
        pB[nt] = TT + ((size_t)(b * DD) + col0 + wn * 32 + nt * 16 + l15) * 3072
                    + rg * 1024 + quad * 8;
#pragma unroll 4
    for (int i = 0; i < 32; i++) {
        int kk = rg * 1024 + i * 32 + quad * 8;   // K index in [0,3072)
        int r  = kk >> 9;                          // relation for this chunk
        int i0 = kk & 511;                         // source index
        short8 af[2], bf[2];
#pragma unroll
        for (int mt = 0; mt < 2; mt++) {
            uint2 cw = *(const uint2*)(pC[mt] + i0);
            union { ushort u[8]; short8 v; } am;
#pragma unroll
            for (int t = 0; t < 8; t++) {
                unsigned int word = (t < 4) ? cw.x : cw.y;
                unsigned int code = (word >> (8 * (t & 3))) & 255u;
                am.u[t] = (code == (unsigned)r) ? 0x3F80 : 0;
            }
            af[mt] = am.v;
        }
#pragma unroll
        for (int nt = 0; nt < 2; nt++) bf[nt] = *(const short8*)(pB[nt] + i * 32);
#pragma unroll
        for (int mt = 0; mt < 2; mt++)
#pragma unroll
            for (int nt = 0; nt < 2; nt++)
                acc[mt][nt] = __builtin_amdgcn_mfma_f32_16x16x32_bf16(
                    af[mt], bf[nt], acc[mt][nt], 0, 0, 0);
    }
#pragma unroll
    for (int mt = 0; mt < 2; mt++)
#pragma unroll
        for (int nt = 0; nt < 2; nt++)
#pragma unroll
            for (int v = 0; v < 4; v++) {
                int j = row0 + wm * 32 + mt * 16 + quad * 4 + v;
                int e = col0 + wn * 32 + nt * 16 + l15;
                atomicAdd(&symOut[((size_t)(b * NN) + j) * DD + e], acc[mt][nt][v]);
            }
}

// ----------------------------------------------------------------- gemm2 --
// symOut(fp32, converted per-lane) @ Wbig^T; LDS-free. Grid (16, 64).
// Col tiles <768: gelu + fused interp reduce (atomicAdd into outI
// pre-loaded with h2b). Else: output projection -> out0.
__global__ __launch_bounds__(256) void gemm2_kernel(
    const float* __restrict__ symOut, const ushort* __restrict__ WbT,
    const float* __restrict__ bbig, const float* __restrict__ h2W,
    float* __restrict__ out0, float* __restrict__ outI)
{
    int tid = threadIdx.x;
    int row0 = blockIdx.y * 64, col0 = blockIdx.x * 64;
    TILE_IDS();
    ACC_INIT();
    const float* pA[2];
#pragma unroll
    for (int mt = 0; mt < 2; mt++)
        pA[mt] = symOut + (size_t)(row0 + wm * 32 + mt * 16 + l15) * DD + quad * 8;
    const ushort* pB[2];
#pragma unroll
    for (int nt = 0; nt < 2; nt++)
        pB[nt] = WbT + (size_t)(col0 + wn * 32 + nt * 16 + l15) * DD + quad * 8;
#pragma unroll
    for (int i = 0; i < 8; i++) {
        short8 af[2], bf[2];
#pragma unroll
        for (int mt = 0; mt < 2; mt++) {
            float4 a0 = *(const float4*)(pA[mt] + i * 32);
            float4 a1 = *(const float4*)(pA[mt] + i * 32 + 4);
            union { ushort u[8]; short8 v; } am;
            am.u[0] = f2bf(a0.x); am.u[1] = f2bf(a0.y);
            am.u[2] = f2bf(a0.z); am.u[3] = f2bf(a0.w);
            am.u[4] = f2bf(a1.x); am.u[5] = f2bf(a1.y);
            am.u[6] = f2bf(a1.z); am.u[7] = f2bf(a1.w);
            af[mt] = am.v;
        }
#pragma unroll
        for (int nt = 0; nt < 2; nt++) bf[nt] = *(const short8*)(pB[nt] + i * 32);
#pragma unroll
        for (int mt = 0; mt < 2; mt++)
#pragma unroll
            for (int nt = 0; nt < 2; nt++)
                acc[mt][nt] = __builtin_amdgcn_mfma_f32_16x16x32_bf16(
                    af[mt], bf[nt], acc[mt][nt], 0, 0, 0);
    }
    if (col0 >= 768) {
#pragma unroll
        for (int nt = 0; nt < 2; nt++) {
            int c = col0 + wn * 32 + nt * 16 + l15;
            float bb = bbig[c];
#pragma unroll
            for (int mt = 0; mt < 2; mt++)
#pragma unroll
                for (int v = 0; v < 4; v++) {
                    int row = row0 + wm * 32 + mt * 16 + quad * 4 + v;
                    out0[(size_t)row * DD + (c - 768)] = acc[mt][nt][v] + bb;
                }
        }
    } else {
        int head = col0 >> 8;
        float part[2][4];
#pragma unroll
        for (int mt = 0; mt < 2; mt++)
#pragma unroll
            for (int v = 0; v < 4; v++) part[mt][v] = 0.f;
#pragma unroll
        for (int nt = 0; nt < 2; nt++) {
            int c = col0 + wn * 32 + nt * 16 + l15;
            float bb = bbig[c];
            float w2 = h2W[c];
#pragma unroll
            for (int mt = 0; mt < 2; mt++)
#pragma unroll
                for (int v = 0; v < 4; v++)
                    part[mt][v] += gelu_exact(acc[mt][nt][v] + bb) * w2;
        }
#pragma unroll
        for (int mt = 0; mt < 2; mt++)
#pragma unroll
            for (int v = 0; v < 4; v++) {
                float p = part[mt][v];
                p += __shfl_xor(p, 1); p += __shfl_xor(p, 2);
                p += __shfl_xor(p, 4); p += __shfl_xor(p, 8);
                if (l15 == 0) {
                    int row = row0 + wm * 32 + mt * 16 + quad * 4 + v;
                    atomicAdd(&outI[head * BNT + row], p);
                }
            }
    }
}

// ---------------------------------------------------------------- launch --
extern "C" void kernel_launch(void* const* d_in, const int* in_sizes, int n_in,
                              void* d_out, int out_size, void* d_ws, size_t ws_size,
                              hipStream_t stream)
{
    const int*   ids  = (const int*)d_in[0];
    const float* pos  = (const float*)d_in[1];
    const float* symt = (const float*)d_in[2];
    const float* layt = (const float*)d_in[3];
    const float* relW = (const float*)d_in[4];
    const float* relb = (const float*)d_in[5];
    const float* h1W  = (const float*)d_in[6];
    const float* h1b  = (const float*)d_in[7];
    const float* h2W  = (const float*)d_in[8];
    const float* h2b  = (const float*)d_in[9];
    const float* outW = (const float*)d_in[10];
    const float* outb = (const float*)d_in[11];
    float* out = (float*)d_out;
    float* ws  = (float*)d_ws;

    ushort* s0b  = (ushort*)(ws + OFF_S0B);
    ushort* TT   = (ushort*)(ws + OFF_TT);
    ushort* WcT  = (ushort*)(ws + OFF_WCT);
    ushort* WbT  = (ushort*)(ws + OFF_WBT);
    float*  bbig = ws + OFF_BB;
    unsigned char* rel = (unsigned char*)(ws + OFF_REL);

    front_kernel<<<6144, 256, 0, stream>>>(ids, pos, symt, layt, relW, h1W, outW,
                                           h1b, outb, h2b, WcT, WbT, bbig,
                                           out + INTERP_OFF, out + SYM_OFF, s0b, rel);
    gemmT_kernel<<<dim3(8, 24, 8), 256, 0, stream>>>(WcT, s0b, relb, TT);
    agg_gemm<<<dim3(4, 8, 24), 256, 0, stream>>>(rel, TT, out + SYM_OFF);
    gemm2_kernel<<<dim3(16, 64), 256, 0, stream>>>(out + SYM_OFF, WbT,
                                                   bbig, h2W,
                                                   out + OUT0_OFF, out + INTERP_OFF);
}

// Round 14
// 150.643 us; speedup vs baseline: 1.2587x; 1.2587x over previous
//
#include <hip/hip_runtime.h>
#include <hip/hip_bf16.h>
#include <math.h>

#define BB 8
#define NN 512
#define DD 256
#define BNT 4096   // B*N

typedef __attribute__((ext_vector_type(8))) short short8;
typedef __attribute__((ext_vector_type(4))) float f32x4;

// Workspace layout (float offsets). ~47 MB (ws is 256 MB).
#define OFF_S0B   0u          // bf16 [4096][256]      s0 row-major (gemmT B)
#define OFF_TT    524288u     // bf16 [8][256][3072]   TT[b][e][r*512+i] = T_r[i][e]+relb_r[e]
#define OFF_WCT   6815744u    // bf16 [256][1536]      WcT[e][r*256+d] = relW[r][d][e]
#define OFF_WBT   7012352u    // bf16 [1024][256]      Wbig^T (c rows, k=d)
#define OFF_BB    7143424u    // fp32 [1024]           h1b|outb
#define OFF_REL   7144448u    // u8   [8][512][512]    relation codes (self=6)
#define OFF_S0F   7668736u    // fp32 [4096][256]      s0 (gemm2 base term)
#define OFF_PART  8717312u    // fp32 [3][4096][256]   agg partials per rg

// d_out layout (floats)
#define OUT0_OFF   0u        // output  [8][512][256]
#define INTERP_OFF 1048576u  // interp  [3][4096]
#define SYM_OFF    1060864u  // symbols [8][512][256]

__device__ __forceinline__ float gelu_exact(float x) {
    return 0.5f * x * (1.0f + erff(x * 0.70710678118654752f));
}

__device__ __forceinline__ ushort f2bf(float x) {
    __hip_bfloat16 h = __float2bfloat16(x);
    union { __hip_bfloat16 b; ushort u; } cv;
    cv.b = h;
    return cv.u;
}

// Branch-free classification (reference if/elif priority, applied in reverse).
__device__ __forceinline__ int rel_of(float dx, float dy) {
    int r = (fabsf(dx) < 0.3f && fabsf(dy) < 0.3f) ? 4 : 5;
    r = (dx >  0.5f) ? 3 : r;
    r = (dx < -0.5f) ? 2 : r;
    r = (dy < -0.5f) ? 1 : r;
    r = (dy >  0.5f) ? 0 : r;
    return r;
}

// ====== 64x64-tile MFMA core (4 waves 2x2), double-buffered LDS ===========
// LDS [chunk(k/8)][row] ushort8 (conflict-free b128 reads; staging loads
// COALESCED per wave — r13 showed per-lane direct loads splinter cache
// lines). Fragments (m89/m91): A: m=lane&15,k=quad*8+j; B: n=lane&15;
// C/D: col=lane&15, row=quad*4+reg.
#define TILE_IDS()                                             \
    const int lane = tid & 63, w = tid >> 6;                   \
    const int wm = w >> 1, wn = w & 1;                         \
    const int quad = lane >> 4, l15 = lane & 15;               \
    const int sm = tid >> 2, sq = tid & 3;

#define MFMA_STEP(Abuf, Bbuf)                                                \
    {                                                                        \
        short8 af[2], bfr[2];                                                \
        _Pragma("unroll")                                                    \
        for (int mt = 0; mt < 2; mt++)                                       \
            af[mt] = *(const short8*)&(Abuf)[(quad * 64 + wm * 32 + mt * 16 + l15) * 8]; \
        _Pragma("unroll")                                                    \
        for (int nt = 0; nt < 2; nt++)                                       \
            bfr[nt] = *(const short8*)&(Bbuf)[(quad * 64 + wn * 32 + nt * 16 + l15) * 8]; \
        _Pragma("unroll")                                                    \
        for (int mt = 0; mt < 2; mt++)                                       \
            _Pragma("unroll")                                                \
            for (int nt = 0; nt < 2; nt++)                                   \
                acc[mt][nt] = __builtin_amdgcn_mfma_f32_16x16x32_bf16(       \
                    af[mt], bfr[nt], acc[mt][nt], 0, 0, 0);                  \
    }

#define ACC_INIT()                                             \
    f32x4 acc[2][2];                                           \
    _Pragma("unroll") for (int mt = 0; mt < 2; mt++)           \
    _Pragma("unroll") for (int nt = 0; nt < 2; nt++)           \
        acc[mt][nt] = (f32x4){0.f, 0.f, 0.f, 0.f};

// ---------------------------------------------------------------- front ---
// Fused prep (blocks 0..1535) + gather (1536..5631) + classify (5632..6143).
__global__ __launch_bounds__(256) void front_kernel(
    const int* __restrict__ ids, const float* __restrict__ positions,
    const float* __restrict__ symt, const float* __restrict__ layt,
    const float* __restrict__ relW, const float* __restrict__ h1W,
    const float* __restrict__ outW, const float* __restrict__ h1b,
    const float* __restrict__ outb, const float* __restrict__ h2b,
    ushort* __restrict__ WcT, ushort* __restrict__ WbT,
    float* __restrict__ bbig, float* __restrict__ outI,
    float* __restrict__ s0f, ushort* __restrict__ s0b,
    unsigned char* __restrict__ rel)
{
    __shared__ float px[NN], py[NN];
    int blk = blockIdx.x, tid = threadIdx.x;
    if (blk < 1536) {
        int idx = blk * 256 + tid;               // 393216
        {
            int e = idx / 1536, k = idx - e * 1536;
            int r = k >> 8, d = k & 255;
            WcT[idx] = f2bf(relW[(r * DD + d) * DD + e]);
        }
        if (idx < 262144) {
            int c = idx >> 8, d = idx & 255;
            float v;
            if (c < 768) { int r = c >> 8, e = c & 255; v = h1W[(r * DD + d) * DD + e]; }
            else         { v = outW[d * DD + (c - 768)]; }
            WbT[idx] = f2bf(v);
        }
        if (idx < 3 * BNT) outI[idx] = h2b[idx >> 12];
        if (idx < 1024) bbig[idx] = (idx < 768) ? h1b[idx] : outb[idx - 768];
    } else if (blk < 5632) {
        int row = blk - 1536;                    // [0,4096)
        int id = ids[row];
        float v = symt[(size_t)id * DD + tid] + layt[(size_t)id * DD + tid];
        s0f[(size_t)row * DD + tid] = v;
        s0b[(size_t)row * DD + tid] = f2bf(v);
    } else {
        int blk2 = blk - 5632;                   // [0,512)
        int b = blk2 >> 6;
        int j0 = (blk2 & 63) << 3;
        int jl = tid >> 5, sub = tid & 31;       // 8 j's x 32 workers x 16 i's
        for (int i = tid; i < NN; i += 256) {
            float2 p = ((const float2*)positions)[b * NN + i];
            px[i] = p.x; py[i] = p.y;
        }
        __syncthreads();
        int j = j0 + jl;
        float xj = px[j], yj = py[j];
        union { unsigned char u8[16]; uint4 v; } codes;
#pragma unroll
        for (int t = 0; t < 16; t++) {
            int i = sub * 16 + t;
            int r = rel_of(xj - px[i], yj - py[i]);
            r = (i == j) ? 6 : r;
            codes.u8[t] = (unsigned char)r;
        }
        *(uint4*)&rel[((size_t)(b * NN + j)) * NN + sub * 16] = codes.v;
    }
}

// ----------------------------------------------------------------- gemmT --
// TT[b][e][r*512+i] = sum_d relW[r][d][e]*s0[b][i][d] + relb[r][e]
// Double-buffered; grid (8 it, 24 rm, 8 b) = 1536 blocks.
__global__ __launch_bounds__(256) void gemmT_kernel(
    const ushort* __restrict__ WcT, const ushort* __restrict__ s0b,
    const float* __restrict__ relb, ushort* __restrict__ TT)
{
    __shared__ ushort Als[2][2048], Bls[2][2048];
    int tid = threadIdx.x;
    int b = blockIdx.z;
    int rowM0 = blockIdx.y * 64;           // in [0,1536): r*256+e
    int col0 = blockIdx.x * 64;            // i tile
    int r = rowM0 >> 8, e0 = rowM0 & 255;
    TILE_IDS();
    ACC_INIT();
    const ushort* gA = WcT + (size_t)(e0 + sm) * 1536 + r * 256 + sq * 8;
    const ushort* gB = s0b + ((size_t)(b * NN) + col0 + sm) * DD + sq * 8;
    const int lo = (sq * 64 + sm) * 8;

    *(uint4*)&Als[0][lo] = *(const uint4*)gA;
    *(uint4*)&Bls[0][lo] = *(const uint4*)gB;
#pragma unroll
    for (int i = 0; i < 8; i++) {
        __syncthreads();
        uint4 av2, bv2;
        if (i < 7) {
            av2 = *(const uint4*)(gA + (i + 1) * 32);
            bv2 = *(const uint4*)(gB + (i + 1) * 32);
        }
        MFMA_STEP(Als[i & 1], Bls[i & 1]);
        if (i < 7) {
            *(uint4*)&Als[(i + 1) & 1][lo] = av2;
            *(uint4*)&Bls[(i + 1) & 1][lo] = bv2;
        }
    }
#pragma unroll
    for (int mt = 0; mt < 2; mt++)
#pragma unroll
        for (int nt = 0; nt < 2; nt++)
#pragma unroll
            for (int v = 0; v < 4; v++) {
                int e = e0 + wm * 32 + mt * 16 + quad * 4 + v;
                int i = col0 + wn * 32 + nt * 16 + l15;
                TT[((size_t)(b * DD) + e) * 3072 + r * 512 + i] =
                    f2bf(acc[mt][nt][v] + relb[r * DD + e]);
            }
}

// ------------------------------------------------------------- agg gemm ---
// PART[rg][b*512+j][e] = sum over K-slice rg of 1[rel(i,j)=r]*TT[...]
// 3 K-slices (rg, K=1024), grid (4 et, 8 jt, 24 b*rg) = 768 blocks.
// Plain stores (no atomics) — gemm2 sums the partials.
__global__ __launch_bounds__(256) void agg_gemm(
    const unsigned char* __restrict__ rel, const ushort* __restrict__ TT,
    float* __restrict__ part)
{
    __shared__ ushort Als[2][2048], Bls[2][2048];
    int tid = threadIdx.x;
    int z = blockIdx.z;
    int b = z / 3, rg = z - b * 3;
    int row0 = blockIdx.y * 64, col0 = blockIdx.x * 64;
    TILE_IDS();
    ACC_INIT();
    const unsigned char* gC = rel + ((size_t)(b * NN + row0 + sm)) * NN;
    const ushort* gB = TT + ((size_t)(b * DD) + col0 + sm) * 3072 + rg * 1024 + sq * 8;
    const int lo = (sq * 64 + sm) * 8;

#define AGG_LOADS(i, cw, bv)                                        \
    cw = *(const uint2*)(gC + (((i) * 32 + sq * 8) & 511));         \
    bv = *(const uint4*)(gB + (i) * 32);

#define AGG_STAGE(i, cw, bv, buf)                                   \
    {                                                               \
        int rr_ = 2 * rg + (((i) * 32) >> 9);                       \
        union alignas(16) { ushort u[8]; uint4 v; } am;             \
        _Pragma("unroll")                                           \
        for (int t = 0; t < 8; t++) {                               \
            unsigned int word = (t < 4) ? cw.x : cw.y;              \
            unsigned int code = (word >> (8 * (t & 3))) & 255u;     \
            am.u[t] = (code == (unsigned)rr_) ? 0x3F80 : 0;         \
        }                                                           \
        *(uint4*)&Als[buf][lo] = am.v;                              \
        *(uint4*)&Bls[buf][lo] = bv;                                \
    }

    uint2 cw0; uint4 bv0;
    AGG_LOADS(0, cw0, bv0);
    AGG_STAGE(0, cw0, bv0, 0);
    for (int i = 0; i < 32; i++) {
        __syncthreads();
        uint2 cw2; uint4 bv2;
        if (i < 31) { AGG_LOADS(i + 1, cw2, bv2); }
        MFMA_STEP(Als[i & 1], Bls[i & 1]);
        if (i < 31) { AGG_STAGE(i + 1, cw2, bv2, (i + 1) & 1); }
    }
#undef AGG_LOADS
#undef AGG_STAGE
    float* dst = part + (size_t)rg * BNT * DD + (size_t)(b * NN) * DD;
#pragma unroll
    for (int mt = 0; mt < 2; mt++)
#pragma unroll
        for (int nt = 0; nt < 2; nt++)
#pragma unroll
            for (int v = 0; v < 4; v++) {
                int j = row0 + wm * 32 + mt * 16 + quad * 4 + v;
                int e = col0 + wn * 32 + nt * 16 + l15;
                dst[(size_t)j * DD + e] = acc[mt][nt][v];
            }
}

// ----------------------------------------------------------------- gemm2 --
// A = s0f + P0 + P1 + P2 (summed fp32 at staging, converted bf16);
// blocks with col-tile 0 also write the sum to symOut (each (row,e) once).
// Col tiles <768: gelu + fused interp reduce (atomicAdd into outI
// pre-loaded with h2b). Else: output projection -> out0.
__global__ __launch_bounds__(256) void gemm2_kernel(
    const float* __restrict__ s0f, const float* __restrict__ part,
    const ushort* __restrict__ WbT, const float* __restrict__ bbig,
    const float* __restrict__ h2W, float* __restrict__ out0,
    float* __restrict__ outI, float* __restrict__ symOut)
{
    __shared__ ushort Als[2][2048], Bls[2][2048];
    int tid = threadIdx.x;
    int row0 = blockIdx.y * 64, col0 = blockIdx.x * 64;
    TILE_IDS();
    ACC_INIT();
    const size_t aoff = (size_t)(row0 + sm) * DD + sq * 8;
    const float* gA  = s0f + aoff;
    const float* gP0 = part + aoff;
    const float* gP1 = part + (size_t)BNT * DD + aoff;
    const float* gP2 = part + (size_t)2 * BNT * DD + aoff;
    float* gS = symOut + aoff;
    const bool wrSym = (blockIdx.x == 0);
    const ushort* gB = WbT + (size_t)(col0 + sm) * DD + sq * 8;
    const int lo = (sq * 64 + sm) * 8;

#define G2_LOADS(i, a0, a1, bv)                                     \
    {                                                               \
        float4 q0 = *(const float4*)(gA + (i) * 32);                \
        float4 q1 = *(const float4*)(gA + (i) * 32 + 4);            \
        float4 u0 = *(const float4*)(gP0 + (i) * 32);               \
        float4 u1 = *(const float4*)(gP0 + (i) * 32 + 4);           \
        float4 v0 = *(const float4*)(gP1 + (i) * 32);               \
        float4 v1 = *(const float4*)(gP1 + (i) * 32 + 4);           \
        float4 w0 = *(const float4*)(gP2 + (i) * 32);               \
        float4 w1 = *(const float4*)(gP2 + (i) * 32 + 4);           \
        a0.x = q0.x + u0.x + v0.x + w0.x;                           \
        a0.y = q0.y + u0.y + v0.y + w0.y;                           \
        a0.z = q0.z + u0.z + v0.z + w0.z;                           \
        a0.w = q0.w + u0.w + v0.w + w0.w;                           \
        a1.x = q1.x + u1.x + v1.x + w1.x;                           \
        a1.y = q1.y + u1.y + v1.y + w1.y;                           \
        a1.z = q1.z + u1.z + v1.z + w1.z;                           \
        a1.w = q1.w + u1.w + v1.w + w1.w;                           \
        if (wrSym) {                                                \
            *(float4*)(gS + (i) * 32) = a0;                         \
            *(float4*)(gS + (i) * 32 + 4) = a1;                     \
        }                                                           \
        bv = *(const uint4*)(gB + (i) * 32);                        \
    }

#define G2_STAGE(a0, a1, bv, buf)                                   \
    {                                                               \
        union alignas(16) { ushort u[8]; uint4 v; } am;             \
        am.u[0] = f2bf(a0.x); am.u[1] = f2bf(a0.y);                 \
        am.u[2] = f2bf(a0.z); am.u[3] = f2bf(a0.w);                 \
        am.u[4] = f2bf(a1.x); am.u[5] = f2bf(a1.y);                 \
        am.u[6] = f2bf(a1.z); am.u[7] = f2bf(a1.w);                 \
        *(uint4*)&Als[buf][lo] = am.v;                              \
        *(uint4*)&Bls[buf][lo] = bv;                                \
    }

    float4 a0, a1; uint4 bv;
    G2_LOADS(0, a0, a1, bv);
    G2_STAGE(a0, a1, bv, 0);
#pragma unroll
    for (int i = 0; i < 8; i++) {
        __syncthreads();
        float4 a0n, a1n; uint4 bvn;
        if (i < 7) { G2_LOADS(i + 1, a0n, a1n, bvn); }
        MFMA_STEP(Als[i & 1], Bls[i & 1]);
        if (i < 7) { G2_STAGE(a0n, a1n, bvn, (i + 1) & 1); }
    }
#undef G2_LOADS
#undef G2_STAGE
    if (col0 >= 768) {
#pragma unroll
        for (int nt = 0; nt < 2; nt++) {
            int c = col0 + wn * 32 + nt * 16 + l15;
            float bb = bbig[c];
#pragma unroll
            for (int mt = 0; mt < 2; mt++)
#pragma unroll
                for (int v = 0; v < 4; v++) {
                    int row = row0 + wm * 32 + mt * 16 + quad * 4 + v;
                    out0[(size_t)row * DD + (c - 768)] = acc[mt][nt][v] + bb;
                }
        }
    } else {
        int head = col0 >> 8;
        float part2[2][4];
#pragma unroll
        for (int mt = 0; mt < 2; mt++)
#pragma unroll
            for (int v = 0; v < 4; v++) part2[mt][v] = 0.f;
#pragma unroll
        for (int nt = 0; nt < 2; nt++) {
            int c = col0 + wn * 32 + nt * 16 + l15;
            float bb = bbig[c];
            float w2 = h2W[c];
#pragma unroll
            for (int mt = 0; mt < 2; mt++)
#pragma unroll
                for (int v = 0; v < 4; v++)
                    part2[mt][v] += gelu_exact(acc[mt][nt][v] + bb) * w2;
        }
#pragma unroll
        for (int mt = 0; mt < 2; mt++)
#pragma unroll
            for (int v = 0; v < 4; v++) {
                float p = part2[mt][v];
                p += __shfl_xor(p, 1); p += __shfl_xor(p, 2);
                p += __shfl_xor(p, 4); p += __shfl_xor(p, 8);
                if (l15 == 0) {
                    int row = row0 + wm * 32 + mt * 16 + quad * 4 + v;
                    atomicAdd(&outI[head * BNT + row], p);
                }
            }
    }
}

// ---------------------------------------------------------------- launch --
extern "C" void kernel_launch(void* const* d_in, const int* in_sizes, int n_in,
                              void* d_out, int out_size, void* d_ws, size_t ws_size,
                              hipStream_t stream)
{
    const int*   ids  = (const int*)d_in[0];
    const float* pos  = (const float*)d_in[1];
    const float* symt = (const float*)d_in[2];
    const float* layt = (const float*)d_in[3];
    const float* relW = (const float*)d_in[4];
    const float* relb = (const float*)d_in[5];
    const float* h1W  = (const float*)d_in[6];
    const float* h1b  = (const float*)d_in[7];
    const float* h2W  = (const float*)d_in[8];
    const float* h2b  = (const float*)d_in[9];
    const float* outW = (const float*)d_in[10];
    const float* outb = (const float*)d_in[11];
    float* out = (float*)d_out;
    float* ws  = (float*)d_ws;

    ushort* s0b  = (ushort*)(ws + OFF_S0B);
    ushort* TT   = (ushort*)(ws + OFF_TT);
    ushort* WcT  = (ushort*)(ws + OFF_WCT);
    ushort* WbT  = (ushort*)(ws + OFF_WBT);
    float*  bbig = ws + OFF_BB;
    unsigned char* rel = (unsigned char*)(ws + OFF_REL);
    float*  s0f  = ws + OFF_S0F;
    float*  partp = ws + OFF_PART;

    front_kernel<<<6144, 256, 0, stream>>>(ids, pos, symt, layt, relW, h1W, outW,
                                           h1b, outb, h2b, WcT, WbT, bbig,
                                           out + INTERP_OFF, s0f, s0b, rel);
    gemmT_kernel<<<dim3(8, 24, 8), 256, 0, stream>>>(WcT, s0b, relb, TT);
    agg_gemm<<<dim3(4, 8, 24), 256, 0, stream>>>(rel, TT, partp);
    gemm2_kernel<<<dim3(16, 64), 256, 0, stream>>>(s0f, partp, WbT, bbig, h2W,
                                                   out + OUT0_OFF,
                                                   out + INTERP_OFF,
                                                   out + SYM_OFF);
}

// Round 15
// 147.468 us; speedup vs baseline: 1.2858x; 1.0215x over previous
//
#include <hip/hip_runtime.h>
#include <hip/hip_bf16.h>
#include <math.h>

#define BB 8
#define NN 512
#define DD 256
#define BNT 4096   // B*N

typedef __attribute__((ext_vector_type(8))) short short8;
typedef __attribute__((ext_vector_type(4))) float f32x4;

// Workspace layout (float offsets). ~18 MB.
#define OFF_S0B   0u          // bf16 [4096][256]      s0 row-major (gemmT B)
#define OFF_TT    524288u     // bf16 [8][256][3072]   TT[b][e][r*512+i] = T_r[i][e]+relb_r[e]
#define OFF_WCT   6815744u    // bf16 [256][1536]      WcT[e][r*256+d] = relW[r][d][e]
#define OFF_WBT   7012352u    // bf16 [1024][256]      Wbig^T (c rows, k=d)
#define OFF_BB    7143424u    // fp32 [1024]           h1b|outb
#define OFF_REL   7144448u    // u8   [8][512][512]    relation codes (self=6)

// d_out layout (floats)
#define OUT0_OFF   0u        // output  [8][512][256]
#define INTERP_OFF 1048576u  // interp  [3][4096]
#define SYM_OFF    1060864u  // symbols [8][512][256]

__device__ __forceinline__ float gelu_exact(float x) {
    return 0.5f * x * (1.0f + erff(x * 0.70710678118654752f));
}

__device__ __forceinline__ ushort f2bf(float x) {
    __hip_bfloat16 h = __float2bfloat16(x);
    union { __hip_bfloat16 b; ushort u; } cv;
    cv.b = h;
    return cv.u;
}

// Branch-free classification (reference if/elif priority, applied in reverse).
__device__ __forceinline__ int rel_of(float dx, float dy) {
    int r = (fabsf(dx) < 0.3f && fabsf(dy) < 0.3f) ? 4 : 5;
    r = (dx >  0.5f) ? 3 : r;
    r = (dx < -0.5f) ? 2 : r;
    r = (dy < -0.5f) ? 1 : r;
    r = (dy >  0.5f) ? 0 : r;
    return r;
}

// ====== 64x64-tile MFMA, FULL-K LDS panel, ONE barrier per block ==========
// LDS 16B units [kchunk][row] (kchunk = k/8). Staging coalesced (r13 showed
// per-lane direct global fragment loads splinter cache lines). Fragments
// (m89/m91): A: m=lane&15,k=quad*8+j; B: n=lane&15; C/D: col=lane&15,
// row=quad*4+reg.
#define TILE_IDS()                                             \
    const int lane = tid & 63, w = tid >> 6;                   \
    const int wm = w >> 1, wn = w & 1;                         \
    const int quad = lane >> 4, l15 = lane & 15;               \
    const int sm = tid >> 2, sq = tid & 3;

#define ACC_INIT()                                             \
    f32x4 acc[2][2];                                           \
    _Pragma("unroll") for (int mt = 0; mt < 2; mt++)           \
    _Pragma("unroll") for (int nt = 0; nt < 2; nt++)           \
        acc[mt][nt] = (f32x4){0.f, 0.f, 0.f, 0.f};

// ---------------------------------------------------------------- front ---
// Fused prep (blocks 0..1535, coalesced reads / scattered writes) +
// gather (1536..5631) + classify (5632..6143).
__global__ __launch_bounds__(256) void front_kernel(
    const int* __restrict__ ids, const float* __restrict__ positions,
    const float* __restrict__ symt, const float* __restrict__ layt,
    const float* __restrict__ relW, const float* __restrict__ h1W,
    const float* __restrict__ outW, const float* __restrict__ h1b,
    const float* __restrict__ outb, const float* __restrict__ h2b,
    ushort* __restrict__ WcT, ushort* __restrict__ WbT,
    float* __restrict__ bbig, float* __restrict__ outI,
    float* __restrict__ symOut, ushort* __restrict__ s0b,
    unsigned char* __restrict__ rel)
{
    __shared__ float px[NN], py[NN];
    int blk = blockIdx.x, tid = threadIdx.x;
    if (blk < 1536) {
        int idx = blk * 256 + tid;               // 393216
        {
            // WcT[e][rd] = relW[rd][e]  (read coalesced, write scattered)
            int rd = idx >> 8, e = idx & 255;
            WcT[(size_t)e * 1536 + rd] = f2bf(relW[idx]);
        }
        if (idx < 196608) {
            // h1W flat [r][d][e] -> WbT[(r*256+e)][d]
            int r = idx >> 16, rem = idx & 65535;
            int d = rem >> 8, e = rem & 255;
            WbT[(size_t)(r * 256 + e) * DD + d] = f2bf(h1W[idx]);
        } else if (idx < 262144) {
            // outW flat [d][c'] -> WbT[768+c'][d]
            int idx2 = idx - 196608;
            int d = idx2 >> 8, c = idx2 & 255;
            WbT[(size_t)(768 + c) * DD + d] = f2bf(outW[idx2]);
        }
        if (idx < 3 * BNT) outI[idx] = h2b[idx >> 12];
        if (idx < 1024) bbig[idx] = (idx < 768) ? h1b[idx] : outb[idx - 768];
    } else if (blk < 5632) {
        int row = blk - 1536;                    // [0,4096)
        int id = ids[row];
        float v = symt[(size_t)id * DD + tid] + layt[(size_t)id * DD + tid];
        symOut[(size_t)row * DD + tid] = v;
        s0b[(size_t)row * DD + tid] = f2bf(v);
    } else {
        int blk2 = blk - 5632;                   // [0,512)
        int b = blk2 >> 6;
        int j0 = (blk2 & 63) << 3;
        int jl = tid >> 5, sub = tid & 31;       // 8 j's x 32 workers x 16 i's
        for (int i = tid; i < NN; i += 256) {
            float2 p = ((const float2*)positions)[b * NN + i];
            px[i] = p.x; py[i] = p.y;
        }
        __syncthreads();
        int j = j0 + jl;
        float xj = px[j], yj = py[j];
        union { unsigned char u8[16]; uint4 v; } codes;
#pragma unroll
        for (int t = 0; t < 16; t++) {
            int i = sub * 16 + t;
            int r = rel_of(xj - px[i], yj - py[i]);
            r = (i == j) ? 6 : r;
            codes.u8[t] = (unsigned char)r;
        }
        *(uint4*)&rel[((size_t)(b * NN + j)) * NN + sub * 16] = codes.v;
    }
}

// ----------------------------------------------------------------- gemmT --
// TT[b][e][r*512+i] = sum_d relW[r][d][e]*s0[b][i][d] + relb[r][e]
// Full-K (256) single-stage LDS panel; ONE barrier per block.
// Grid (8 it, 24 rm, 8 b) = 1536 blocks; 64 KB LDS -> 2 blocks/CU.
__global__ __launch_bounds__(256) void gemmT_kernel(
    const ushort* __restrict__ WcT, const ushort* __restrict__ s0b,
    const float* __restrict__ relb, ushort* __restrict__ TT)
{
    __shared__ ushort Als[16384], Bls[16384];    // 32 kchunks x 64 rows x 8
    int tid = threadIdx.x;
    int b = blockIdx.z;
    int rowM0 = blockIdx.y * 64;           // in [0,1536): r*256+e
    int col0 = blockIdx.x * 64;            // i tile
    int r = rowM0 >> 8, e0 = rowM0 & 255;
    TILE_IDS();
    ACC_INIT();
    const ushort* gA = WcT + (size_t)(e0 + sm) * 1536 + r * 256 + sq * 8;
    const ushort* gB = s0b + ((size_t)(b * NN) + col0 + sm) * DD + sq * 8;

    uint4 av[8], bv[8];
#pragma unroll
    for (int i = 0; i < 8; i++) {
        av[i] = *(const uint4*)(gA + i * 32);
        bv[i] = *(const uint4*)(gB + i * 32);
    }
#pragma unroll
    for (int i = 0; i < 8; i++) {
        *(uint4*)&Als[((i * 4 + sq) * 64 + sm) * 8] = av[i];
        *(uint4*)&Bls[((i * 4 + sq) * 64 + sm) * 8] = bv[i];
    }
    __syncthreads();
#pragma unroll
    for (int kk = 0; kk < 8; kk++) {
        short8 af[2], bf[2];
#pragma unroll
        for (int mt = 0; mt < 2; mt++)
            af[mt] = *(const short8*)&Als[((kk * 4 + quad) * 64 + wm * 32 + mt * 16 + l15) * 8];
#pragma unroll
        for (int nt = 0; nt < 2; nt++)
            bf[nt] = *(const short8*)&Bls[((kk * 4 + quad) * 64 + wn * 32 + nt * 16 + l15) * 8];
#pragma unroll
        for (int mt = 0; mt < 2; mt++)
#pragma unroll
            for (int nt = 0; nt < 2; nt++)
                acc[mt][nt] = __builtin_amdgcn_mfma_f32_16x16x32_bf16(
                    af[mt], bf[nt], acc[mt][nt], 0, 0, 0);
    }
#pragma unroll
    for (int mt = 0; mt < 2; mt++)
#pragma unroll
        for (int nt = 0; nt < 2; nt++)
#pragma unroll
            for (int v = 0; v < 4; v++) {
                int e = e0 + wm * 32 + mt * 16 + quad * 4 + v;
                int i = col0 + wn * 32 + nt * 16 + l15;
                TT[((size_t)(b * DD) + e) * 3072 + r * 512 + i] =
                    f2bf(acc[mt][nt][v] + relb[r * DD + e]);
            }
}

// ------------------------------------------------------------- agg gemm ---
// symOut[b*512+j][e] += sum_{r,i} 1[rel(i,j)=r] * TT[b][e][r*512+i]
// Codes staged ONCE in padded LDS (528B rows -> conflict-free b64 reads);
// B double-buffered at BK=128 -> 8 barriers/block (was 32). A one-hot built
// from LDS codes. 3 K-slices (rg, K=1024), grid (4 et, 8 jt, 24 b*rg).
__global__ __launch_bounds__(256) void agg_gemm(
    const unsigned char* __restrict__ rel, const ushort* __restrict__ TT,
    float* __restrict__ symOut)
{
    __shared__ unsigned char CL[64 * 528];       // codes, padded stride
    __shared__ ushort Bls[2][8192];              // 16 kchunks x 64 cols x 8
    int tid = threadIdx.x;
    int z = blockIdx.z;
    int b = z / 3, rg = z - b * 3;
    int row0 = blockIdx.y * 64, col0 = blockIdx.x * 64;
    TILE_IDS();
    ACC_INIT();
    // stage codes: 64 rows x 512B = 32KB contiguous in global
    {
        const unsigned char* gC = rel + ((size_t)(b * NN + row0)) * NN;
#pragma unroll
        for (int i = 0; i < 8; i++) {
            int linear = i * 256 + tid;          // 2048 x 16B chunks
            int row = linear >> 5, off = linear & 31;
            *(uint4*)&CL[row * 528 + off * 16] = *(const uint4*)(gC + linear * 16);
        }
    }
    const ushort* gB = TT + ((size_t)(b * DD) + col0 + sm) * 3072 + rg * 1024 + sq * 8;

#define AGB_LOAD(ko, bv)                                                     \
    _Pragma("unroll")                                                        \
    for (int i = 0; i < 4; i++) bv[i] = *(const uint4*)(gB + (ko) * 128 + i * 32);
#define AGB_STORE(bv, buf)                                                   \
    _Pragma("unroll")                                                        \
    for (int i = 0; i < 4; i++)                                              \
        *(uint4*)&Bls[buf][((i * 4 + sq) * 64 + sm) * 8] = bv[i];

    uint4 bv0[4];
    AGB_LOAD(0, bv0);
    AGB_STORE(bv0, 0);
#pragma unroll
    for (int ko = 0; ko < 8; ko++) {
        __syncthreads();                          // codes (ko=0) + B buffer ready
        uint4 bvn[4];
        if (ko < 7) { AGB_LOAD(ko + 1, bvn); }
#pragma unroll
        for (int kk = 0; kk < 4; kk++) {
            int klocal = ko * 128 + kk * 32;
            int r = 2 * rg + (klocal >> 9);       // wave-uniform
            int il = (klocal + quad * 8) & 511;
            short8 af[2], bf[2];
#pragma unroll
            for (int mt = 0; mt < 2; mt++) {
                int rowf = wm * 32 + mt * 16 + l15;
                uint2 cw = *(const uint2*)&CL[rowf * 528 + il];
                union { ushort u[8]; short8 v; } am;
#pragma unroll
                for (int t = 0; t < 8; t++) {
                    unsigned int word = (t < 4) ? cw.x : cw.y;
                    unsigned int code = (word >> (8 * (t & 3))) & 255u;
                    am.u[t] = (code == (unsigned)r) ? 0x3F80 : 0;
                }
                af[mt] = am.v;
            }
#pragma unroll
            for (int nt = 0; nt < 2; nt++)
                bf[nt] = *(const short8*)&Bls[ko & 1][((kk * 4 + quad) * 64 + wn * 32 + nt * 16 + l15) * 8];
#pragma unroll
            for (int mt = 0; mt < 2; mt++)
#pragma unroll
                for (int nt = 0; nt < 2; nt++)
                    acc[mt][nt] = __builtin_amdgcn_mfma_f32_16x16x32_bf16(
                        af[mt], bf[nt], acc[mt][nt], 0, 0, 0);
        }
        if (ko < 7) { AGB_STORE(bvn, (ko + 1) & 1); }
    }
#undef AGB_LOAD
#undef AGB_STORE
#pragma unroll
    for (int mt = 0; mt < 2; mt++)
#pragma unroll
        for (int nt = 0; nt < 2; nt++)
#pragma unroll
            for (int v = 0; v < 4; v++) {
                int j = row0 + wm * 32 + mt * 16 + quad * 4 + v;
                int e = col0 + wn * 32 + nt * 16 + l15;
                atomicAdd(&symOut[((size_t)(b * NN) + j) * DD + e], acc[mt][nt][v]);
            }
}

// ----------------------------------------------------------------- gemm2 --
// symOut(fp32->bf16 at staging) @ Wbig^T. Full-K (256) single-stage panel,
// ONE barrier per block. Grid (16, 64) = 1024 blocks; 64 KB LDS.
// Col tiles <768: gelu + fused interp reduce (atomicAdd into outI
// pre-loaded with h2b). Else: output projection -> out0.
__global__ __launch_bounds__(256) void gemm2_kernel(
    const float* __restrict__ symOut, const ushort* __restrict__ WbT,
    const float* __restrict__ bbig, const float* __restrict__ h2W,
    float* __restrict__ out0, float* __restrict__ outI)
{
    __shared__ ushort Als[16384], Bls[16384];
    int tid = threadIdx.x;
    int row0 = blockIdx.y * 64, col0 = blockIdx.x * 64;
    TILE_IDS();
    ACC_INIT();
    const float*  gA = symOut + (size_t)(row0 + sm) * DD + sq * 8;
    const ushort* gB = WbT    + (size_t)(col0 + sm) * DD + sq * 8;

#pragma unroll
    for (int half = 0; half < 2; half++) {
        float4 a0[4], a1[4]; uint4 bv[4];
#pragma unroll
        for (int i = 0; i < 4; i++) {
            int c = half * 4 + i;
            a0[i] = *(const float4*)(gA + c * 32);
            a1[i] = *(const float4*)(gA + c * 32 + 4);
            bv[i] = *(const uint4*)(gB + c * 32);
        }
#pragma unroll
        for (int i = 0; i < 4; i++) {
            int c = half * 4 + i;
            union alignas(16) { ushort u[8]; uint4 v; } am;
            am.u[0] = f2bf(a0[i].x); am.u[1] = f2bf(a0[i].y);
            am.u[2] = f2bf(a0[i].z); am.u[3] = f2bf(a0[i].w);
            am.u[4] = f2bf(a1[i].x); am.u[5] = f2bf(a1[i].y);
            am.u[6] = f2bf(a1[i].z); am.u[7] = f2bf(a1[i].w);
            *(uint4*)&Als[((c * 4 + sq) * 64 + sm) * 8] = am.v;
            *(uint4*)&Bls[((c * 4 + sq) * 64 + sm) * 8] = bv[i];
        }
    }
    __syncthreads();
#pragma unroll
    for (int kk = 0; kk < 8; kk++) {
        short8 af[2], bf[2];
#pragma unroll
        for (int mt = 0; mt < 2; mt++)
            af[mt] = *(const short8*)&Als[((kk * 4 + quad) * 64 + wm * 32 + mt * 16 + l15) * 8];
#pragma unroll
        for (int nt = 0; nt < 2; nt++)
            bf[nt] = *(const short8*)&Bls[((kk * 4 + quad) * 64 + wn * 32 + nt * 16 + l15) * 8];
#pragma unroll
        for (int mt = 0; mt < 2; mt++)
#pragma unroll
            for (int nt = 0; nt < 2; nt++)
                acc[mt][nt] = __builtin_amdgcn_mfma_f32_16x16x32_bf16(
                    af[mt], bf[nt], acc[mt][nt], 0, 0, 0);
    }
    if (col0 >= 768) {
#pragma unroll
        for (int nt = 0; nt < 2; nt++) {
            int c = col0 + wn * 32 + nt * 16 + l15;
            float bb = bbig[c];
#pragma unroll
            for (int mt = 0; mt < 2; mt++)
#pragma unroll
                for (int v = 0; v < 4; v++) {
                    int row = row0 + wm * 32 + mt * 16 + quad * 4 + v;
                    out0[(size_t)row * DD + (c - 768)] = acc[mt][nt][v] + bb;
                }
        }
    } else {
        int head = col0 >> 8;
        float part[2][4];
#pragma unroll
        for (int mt = 0; mt < 2; mt++)
#pragma unroll
            for (int v = 0; v < 4; v++) part[mt][v] = 0.f;
#pragma unroll
        for (int nt = 0; nt < 2; nt++) {
            int c = col0 + wn * 32 + nt * 16 + l15;
            float bb = bbig[c];
            float w2 = h2W[c];
#pragma unroll
            for (int mt = 0; mt < 2; mt++)
#pragma unroll
                for (int v = 0; v < 4; v++)
                    part[mt][v] += gelu_exact(acc[mt][nt][v] + bb) * w2;
        }
#pragma unroll
        for (int mt = 0; mt < 2; mt++)
#pragma unroll
            for (int v = 0; v < 4; v++) {
                float p = part[mt][v];
                p += __shfl_xor(p, 1); p += __shfl_xor(p, 2);
                p += __shfl_xor(p, 4); p += __shfl_xor(p, 8);
                if (l15 == 0) {
                    int row = row0 + wm * 32 + mt * 16 + quad * 4 + v;
                    atomicAdd(&outI[head * BNT + row], p);
                }
            }
    }
}

// ---------------------------------------------------------------- launch --
extern "C" void kernel_launch(void* const* d_in, const int* in_sizes, int n_in,
                              void* d_out, int out_size, void* d_ws, size_t ws_size,
                              hipStream_t stream)
{
    const int*   ids  = (const int*)d_in[0];
    const float* pos  = (const float*)d_in[1];
    const float* symt = (const float*)d_in[2];
    const float* layt = (const float*)d_in[3];
    const float* relW = (const float*)d_in[4];
    const float* relb = (const float*)d_in[5];
    const float* h1W  = (const float*)d_in[6];
    const float* h1b  = (const float*)d_in[7];
    const float* h2W  = (const float*)d_in[8];
    const float* h2b  = (const float*)d_in[9];
    const float* outW = (const float*)d_in[10];
    const float* outb = (const float*)d_in[11];
    float* out = (float*)d_out;
    float* ws  = (float*)d_ws;

    ushort* s0b  = (ushort*)(ws + OFF_S0B);
    ushort* TT   = (ushort*)(ws + OFF_TT);
    ushort* WcT  = (ushort*)(ws + OFF_WCT);
    ushort* WbT  = (ushort*)(ws + OFF_WBT);
    float*  bbig = ws + OFF_BB;
    unsigned char* rel = (unsigned char*)(ws + OFF_REL);

    front_kernel<<<6144, 256, 0, stream>>>(ids, pos, symt, layt, relW, h1W, outW,
                                           h1b, outb, h2b, WcT, WbT, bbig,
                                           out + INTERP_OFF, out + SYM_OFF, s0b, rel);
    gemmT_kernel<<<dim3(8, 24, 8), 256, 0, stream>>>(WcT, s0b, relb, TT);
    agg_gemm<<<dim3(4, 8, 24), 256, 0, stream>>>(rel, TT, out + SYM_OFF);
    gemm2_kernel<<<dim3(16, 64), 256, 0, stream>>>(out + SYM_OFF, WbT,
                                                   bbig, h2W,
                                                   out + OUT0_OFF, out + INTERP_OFF);
}